// Round 1
// baseline (678.391 us; speedup 1.0000x reference)
//
#include <hip/hip_runtime.h>
#include <cstdint>
#include <cstddef>

#define BB 128
#define TT 512
#define DD 100
#define HH 100
#define NG 400   // 4*H
#define LL 25
#define F_LOG2E 1.44269504088896340736f
#define F_LN2   0.69314718055994530942f

typedef __decltype(__builtin_amdgcn_cvt_pkrtz(0.f, 0.f)) h2_t;

__device__ __forceinline__ h2_t bc_h2(unsigned int u) {
  return __builtin_bit_cast(h2_t, u);
}

__device__ __forceinline__ float fdot2(h2_t a, h2_t b, float c) {
#if defined(__has_builtin)
#if __has_builtin(__builtin_amdgcn_fdot2)
  return __builtin_amdgcn_fdot2(a, b, c, false);
#else
  return c + (float)a[0] * (float)b[0] + (float)a[1] * (float)b[1];
#endif
#else
  return c + (float)a[0] * (float)b[0] + (float)a[1] * (float)b[1];
#endif
}

__device__ __forceinline__ float fexp2(float x) { return __builtin_amdgcn_exp2f(x); }
__device__ __forceinline__ float flog2(float x) { return __builtin_amdgcn_logf(x); }
__device__ __forceinline__ float frcp(float x)  { return __builtin_amdgcn_rcpf(x); }

__device__ __forceinline__ float sigmoid_f(float x) {
  return frcp(1.f + fexp2(-F_LOG2E * x));
}
__device__ __forceinline__ float tanh_f(float x) {
  float e = fexp2(2.f * F_LOG2E * x);
  return 1.f - 2.f * frcp(e + 1.f);
}

__device__ __forceinline__ float rl(float v, int l) {
  return __builtin_bit_cast(float, __builtin_amdgcn_readlane(__builtin_bit_cast(int, v), l));
}

// ---------------------------------------------------------------------------
// BiLSTM scan: one block per (batch, direction). 512 threads.
// Threads 0..399: gate j (weights W_ih[j,:], W_hh[j,:] in registers as f16x2).
// Threads 448..497: prefetch next x row into LDS (f16x2 packed).
// Threads 0..99: cell update, h broadcast via LDS, h store to global (f32).
// ---------------------------------------------------------------------------
__global__ __launch_bounds__(512, 2) void lstm_scan(
    const int* __restrict__ tok, const float* __restrict__ emb,
    const float* __restrict__ w_ih_f, const float* __restrict__ w_hh_f,
    const float* __restrict__ b_ih_f, const float* __restrict__ b_hh_f,
    const float* __restrict__ w_ih_b, const float* __restrict__ w_hh_b,
    const float* __restrict__ b_ih_b, const float* __restrict__ b_hh_b,
    float* __restrict__ hc)
{
  const int tid = threadIdx.x;
  const int b   = blockIdx.x & 127;
  const int dir = blockIdx.x >> 7;

  const float* w_ih = dir ? w_ih_b : w_ih_f;
  const float* w_hh = dir ? w_hh_b : w_hh_f;
  const float* b_ih = dir ? b_ih_b : b_ih_f;
  const float* b_hh = dir ? b_hh_b : b_hh_f;

  __shared__ __align__(16) unsigned int xs[2][64];  // 50 used h2-pairs + pad
  __shared__ __align__(16) unsigned int hls[64];    // packed f16 h[100] + pad
  __shared__ float gl[NG];                          // activated gates

  h2_t wih[50], whh[50];
  float bias = 0.f;
  if (tid < NG) {
    const float4* wi = (const float4*)(w_ih + tid * DD);
    const float4* wh = (const float4*)(w_hh + tid * DD);
#pragma unroll
    for (int kk = 0; kk < 25; ++kk) {
      float4 a = wi[kk];
      wih[2 * kk]     = __builtin_amdgcn_cvt_pkrtz(a.x, a.y);
      wih[2 * kk + 1] = __builtin_amdgcn_cvt_pkrtz(a.z, a.w);
      float4 c = wh[kk];
      whh[2 * kk]     = __builtin_amdgcn_cvt_pkrtz(c.x, c.y);
      whh[2 * kk + 1] = __builtin_amdgcn_cvt_pkrtz(c.z, c.w);
    }
    bias = b_ih[tid] + b_hh[tid];
  }

  // init LDS: h = 0, zero padding words
  if (tid < 2) { xs[0][50 + tid] = 0u; xs[1][50 + tid] = 0u; hls[50 + tid] = 0u; }
  if (tid < 50) hls[tid] = 0u;  // h[0..99] = 0 (packed halves)

  const int base = b * TT;
  // initial x load for first timestep
  if (tid >= 448 && tid < 498) {
    int tt0 = dir ? (TT - 1) : 0;
    int i = tid - 448;
    int tk = tok[base + tt0];
    float2 v = ((const float2*)(emb + (size_t)tk * DD))[i];
    xs[0][i] = __builtin_bit_cast(unsigned int, __builtin_amdgcn_cvt_pkrtz(v.x, v.y));
  }
  __syncthreads();

  float cst = 0.f;  // cell state (threads 0..99)
  float* hcb = hc + (size_t)base * 200 + dir * 100;

  for (int t = 0; t < TT; ++t) {
    const int buf = t & 1;
    const int tt  = dir ? (TT - 1 - t) : t;

    if (tid < NG) {
      float acc = bias;
      const unsigned int* xp = xs[buf];
#pragma unroll
      for (int g = 0; g < 13; ++g) {
        uint4 u = ((const uint4*)xp)[g];
        const int k = 4 * g;
        acc = fdot2(wih[k], bc_h2(u.x), acc);
        acc = fdot2(wih[k + 1], bc_h2(u.y), acc);
        if (k + 2 < 50) acc = fdot2(wih[k + 2], bc_h2(u.z), acc);
        if (k + 3 < 50) acc = fdot2(wih[k + 3], bc_h2(u.w), acc);
      }
#pragma unroll
      for (int g = 0; g < 13; ++g) {
        uint4 u = ((const uint4*)hls)[g];
        const int k = 4 * g;
        acc = fdot2(whh[k], bc_h2(u.x), acc);
        acc = fdot2(whh[k + 1], bc_h2(u.y), acc);
        if (k + 2 < 50) acc = fdot2(whh[k + 2], bc_h2(u.z), acc);
        if (k + 3 < 50) acc = fdot2(whh[k + 3], bc_h2(u.w), acc);
      }
      // activation: gates [0:100)=i sig, [100:200)=f sig, [200:300)=g tanh, [300:400)=o sig
      float av = (tid >= 200 && tid < 300) ? tanh_f(acc) : sigmoid_f(acc);
      gl[tid] = av;
    } else if (tid >= 448 && tid < 498 && t < TT - 1) {
      int ttn = dir ? (TT - 2 - t) : (t + 1);
      int i = tid - 448;
      int tk = tok[base + ttn];
      float2 v = ((const float2*)(emb + (size_t)tk * DD))[i];
      xs[buf ^ 1][i] = __builtin_bit_cast(unsigned int, __builtin_amdgcn_cvt_pkrtz(v.x, v.y));
    }
    __syncthreads();

    if (tid < HH) {
      float gi = gl[tid], gf = gl[tid + 100], gg = gl[tid + 200], go = gl[tid + 300];
      cst = gf * cst + gi * gg;
      float hv = go * tanh_f(cst);
      ((__fp16*)hls)[tid] = (__fp16)hv;
      hcb[(size_t)tt * 200 + tid] = hv;
    }
    __syncthreads();
  }
}

// ---------------------------------------------------------------------------
// Emissions: em[m, l] = b_tag[l] + sum_k hc[m,k] * w_tag[l,k], m = b*T+t
// Block: 64 rows staged in LDS (stride 201 -> only free 2-way conflicts).
// ---------------------------------------------------------------------------
__global__ __launch_bounds__(256, 2) void emis_kernel(
    const float* __restrict__ hc, const float* __restrict__ w_tag,
    const float* __restrict__ b_tag, float* __restrict__ em)
{
  __shared__ float hsh[64 * 201];
  const int tid = threadIdx.x;
  const size_t m0 = (size_t)blockIdx.x * 64;

  for (int i = tid; i < 64 * 200; i += 256) {
    int r = i / 200;
    int k = i - r * 200;
    hsh[r * 201 + k] = hc[m0 * 200 + i];
  }
  __syncthreads();

  const int r = tid & 63, q = tid >> 6;
  int lidx[7];
  bool lv[7];
  float acc[7];
#pragma unroll
  for (int ii = 0; ii < 7; ++ii) {
    int l = q + 4 * ii;
    lv[ii] = (l < LL);
    lidx[ii] = lv[ii] ? l : 0;
    acc[ii] = lv[ii] ? b_tag[lidx[ii]] : 0.f;
  }
  const float* hrow = hsh + r * 201;
#pragma unroll 4
  for (int k = 0; k < 200; ++k) {
    float hv = hrow[k];
#pragma unroll
    for (int ii = 0; ii < 7; ++ii)
      acc[ii] += hv * w_tag[lidx[ii] * 200 + k];
  }
#pragma unroll
  for (int ii = 0; ii < 7; ++ii)
    if (lv[ii]) em[(m0 + r) * LL + lidx[ii]] = acc[ii];
}

// ---------------------------------------------------------------------------
// CRF gold path score: fully parallel sum over t, one block per batch elem.
// ---------------------------------------------------------------------------
__global__ __launch_bounds__(512, 2) void crf_gold(
    const int* __restrict__ tags, const int* __restrict__ lengths,
    const float* __restrict__ em, const float* __restrict__ trans,
    const float* __restrict__ startt, const float* __restrict__ endt,
    float* __restrict__ gold)
{
  const int b = blockIdx.x, t = threadIdx.x;
  const int len = lengths[b];
  float term = 0.f;
  if (t < len) {
    int tg = tags[b * TT + t];
    float e = em[((size_t)b * TT + t) * LL + tg];
    if (t == 0) term = startt[tg] + e;
    else        term = trans[tags[b * TT + t - 1] * LL + tg] + e;
    if (t == len - 1) term += endt[tg];
  }
  __shared__ float red[8];
  for (int o = 32; o > 0; o >>= 1) term += __shfl_down(term, o);
  if ((t & 63) == 0) red[t >> 6] = term;
  __syncthreads();
  if (t == 0) {
    float s = 0.f;
#pragma unroll
    for (int w = 0; w < 8; ++w) s += red[w];
    gold[b] = s;
  }
}

// ---------------------------------------------------------------------------
// CRF partition: split scan. side 0 = alpha forward over t=0..255,
// side 1 = beta backward over t=511..255. logZ = lse(alpha_255 + beta_255).
// One wave per (b, side). Lane l holds alpha[l]/beta[l]. log2 domain.
// Per-step lane-0 shift keeps exp2 args bounded (spread <= ~2).
// ---------------------------------------------------------------------------
__global__ __launch_bounds__(64, 4) void crf_scan(
    const float* __restrict__ em, const float* __restrict__ trans,
    const float* __restrict__ startt, const float* __restrict__ endt,
    float* __restrict__ ab)
{
  const int lane = threadIdx.x;
  const int b    = blockIdx.x >> 1;
  const int side = blockIdx.x & 1;
  const int lp   = (lane < LL) ? lane : 0;
  const float* emb_ = em + (size_t)b * TT * LL;

  float tc[LL];
#pragma unroll
  for (int l = 0; l < LL; ++l)
    tc[l] = (side == 0 ? trans[l * LL + lp] : trans[lp * LL + l]) * F_LOG2E;

  float a, C = 0.f;
  if (side == 0) {
    a = (startt[lp] + emb_[lp]) * F_LOG2E;
    for (int t = 1; t < 256; ++t) {
      float emv = emb_[t * LL + lp];
      float s = rl(a, 0);
      a -= s; C += s;
      float s0 = 0.f, s1 = 0.f, s2 = 0.f, s3 = 0.f;
#pragma unroll
      for (int l = 0; l < LL; ++l) {
        float al = rl(a, l);
        float e = fexp2(al + tc[l]);
        if ((l & 3) == 0) s0 += e; else if ((l & 3) == 1) s1 += e;
        else if ((l & 3) == 2) s2 += e; else s3 += e;
      }
      a = flog2((s0 + s1) + (s2 + s3)) + emv * F_LOG2E;
    }
  } else {
    a = endt[lp] * F_LOG2E;
    for (int step = 0; step < 256; ++step) {
      int t1 = 511 - step;  // em time index t+1: 511 down to 256
      float v = a + emb_[t1 * LL + lp] * F_LOG2E;
      float s = rl(v, 0);
      v -= s; C += s;
      float s0 = 0.f, s1 = 0.f, s2 = 0.f, s3 = 0.f;
#pragma unroll
      for (int l = 0; l < LL; ++l) {
        float vl = rl(v, l);
        float e = fexp2(vl + tc[l]);
        if ((l & 3) == 0) s0 += e; else if ((l & 3) == 1) s1 += e;
        else if ((l & 3) == 2) s2 += e; else s3 += e;
      }
      a = flog2((s0 + s1) + (s2 + s3));
    }
  }
  if (lane < LL)
    ab[((size_t)b * 2 + side) * LL + lane] = (a + C) * F_LN2;
}

// ---------------------------------------------------------------------------
// Final: logZ_b = lse(alpha+beta), nll_b = logZ_b - gold_b, out = sum_b nll_b
// ---------------------------------------------------------------------------
__global__ __launch_bounds__(128, 4) void crf_final(
    const float* __restrict__ ab, const float* __restrict__ gold,
    float* __restrict__ out)
{
  const int b = threadIdx.x;
  float v[LL];
  float m = -1e30f;
#pragma unroll
  for (int l = 0; l < LL; ++l) {
    v[l] = ab[((size_t)b * 2) * LL + l] + ab[((size_t)b * 2 + 1) * LL + l];
    m = fmaxf(m, v[l]);
  }
  float s = 0.f;
#pragma unroll
  for (int l = 0; l < LL; ++l) s += fexp2((v[l] - m) * F_LOG2E);
  float nll = (m + flog2(s) * F_LN2) - gold[b];

  for (int o = 32; o > 0; o >>= 1) nll += __shfl_down(nll, o);
  __shared__ float r2[2];
  if ((b & 63) == 0) r2[b >> 6] = nll;
  __syncthreads();
  if (b == 0) out[0] = r2[0] + r2[1];
}

extern "C" void kernel_launch(void* const* d_in, const int* in_sizes, int n_in,
                              void* d_out, int out_size, void* d_ws, size_t ws_size,
                              hipStream_t stream) {
  const int*   tok   = (const int*)d_in[0];
  const int*   tags  = (const int*)d_in[1];
  const int*   lens  = (const int*)d_in[2];
  const float* emb   = (const float*)d_in[3];
  const float* wif   = (const float*)d_in[4];
  const float* whf   = (const float*)d_in[5];
  const float* bif   = (const float*)d_in[6];
  const float* bhf   = (const float*)d_in[7];
  const float* wib   = (const float*)d_in[8];
  const float* whb   = (const float*)d_in[9];
  const float* bib   = (const float*)d_in[10];
  const float* bhb   = (const float*)d_in[11];
  const float* wtag  = (const float*)d_in[12];
  const float* btag  = (const float*)d_in[13];
  const float* trans = (const float*)d_in[14];
  const float* st    = (const float*)d_in[15];
  const float* en    = (const float*)d_in[16];

  float* ws   = (float*)d_ws;
  float* hc   = ws;                         // 128*512*200      = 13,107,200 f32
  float* em   = ws + 13107200;              // 128*512*25       =  1,638,400 f32
  float* gold = ws + 13107200 + 1638400;    // 128 f32
  float* ab   = gold + 128;                 // 128*2*25 = 6400 f32

  lstm_scan<<<256, 512, 0, stream>>>(tok, emb, wif, whf, bif, bhf,
                                     wib, whb, bib, bhb, hc);
  emis_kernel<<<1024, 256, 0, stream>>>(hc, wtag, btag, em);
  crf_gold<<<128, 512, 0, stream>>>(tags, lens, em, trans, st, en, gold);
  crf_scan<<<256, 64, 0, stream>>>(em, trans, st, en, ab);
  crf_final<<<1, 128, 0, stream>>>(ab, gold, (float*)d_out);
}